// Round 2
// baseline (1084.725 us; speedup 1.0000x reference)
//
#include <hip/hip_runtime.h>
#include <math.h>

// FFT conv2d: out = irfft2( einsum("bchw,ochw->bohw", rfft2(x), rfft2(w)) )
// B=16, C=32, O=32, H=W=256. fp32.
// Freq layout: flat[(row*256 + h)*PITCH + wb], row = b*32+c (or o*32+c / b*32+o),
// wb in [0,129); PITCH=136 complex keeps every (row,h) line 64B-aligned.
//
// R1: einsum register-prefetch double-buffer (hide HBM latency under compute),
// nyq merged into einsum (grid y==8), col-FFT tail merged (grid y==8).
// 5 dispatches total.

#define PITCH 136
#define SW(i) ((i) + ((i) >> 4))   // row-FFT LDS swizzle; region = 272 float2

__device__ __forceinline__ int drev4(int x) {  // base-4 digit reversal of 8-bit x
  int r = (int)(__brev((unsigned)x) >> 24);
  return ((r & 0x55) << 1) | ((r >> 1) & 0x55);
}

// tw[n] = exp(sign * 2*pi*i * n / 256), n in [0,256)
__device__ __forceinline__ void fill_tw256(float2* tw, float sign, int tid) {
  float ang = sign * 6.2831853071795864769f * (float)tid * (1.0f / 256.0f);
  float s, c;
  __sincosf(ang, &s, &c);
  tw[tid] = make_float2(c, s);
}

__device__ __forceinline__ float2 cmul(float2 a, float2 b) {
  return make_float2(fmaf(a.x, b.x, -(a.y * b.y)), fmaf(a.x, b.y, a.y * b.x));
}

// radix-4 DIT butterfly: a_c = x_c * t_c (t0=1), y_q = sum_c a_c * w4^(q*c),
// w4 = exp(SIGN*2*pi*i/4) = SIGN*i
template <int SIGN>
__device__ __forceinline__ void bfly4(float2 x0, float2 x1, float2 x2, float2 x3,
                                      float2 t1, float2 t2, float2 t3,
                                      float2& y0, float2& y1, float2& y2, float2& y3) {
  float2 a1 = cmul(x1, t1);
  float2 a2 = cmul(x2, t2);
  float2 a3 = cmul(x3, t3);
  float Ax = x0.x + a2.x, Ay = x0.y + a2.y;
  float Bx = x0.x - a2.x, By = x0.y - a2.y;
  float Cx = a1.x + a3.x, Cy = a1.y + a3.y;
  float Dx = a1.x - a3.x, Dy = a1.y - a3.y;
  y0 = make_float2(Ax + Cx, Ay + Cy);
  y2 = make_float2(Ax - Cx, Ay - Cy);
  if (SIGN == 1) {
    y1 = make_float2(Bx - Dy, By + Dx);
    y3 = make_float2(Bx + Dy, By - Dx);
  } else {
    y1 = make_float2(Bx + Dy, By - Dx);
    y3 = make_float2(Bx - Dy, By + Dx);
  }
}

// ---------------- forward real FFT along W ---------------------------------
// 8 real rows per 256-thread block = 4 packed complex FFTs (z = rowA + i*rowB).
// Handles both x (blocks [0,16384)) and w (blocks [16384,49152)).
__global__ __launch_bounds__(256) void rfft_rows(const float* __restrict__ xin,
                                                 const float* __restrict__ win,
                                                 float2* __restrict__ xout,
                                                 float2* __restrict__ wout) {
  __shared__ float2 sc[4 * 272];
  __shared__ float2 tw[256];
  const int tid = threadIdx.x;
  fill_tw256(tw, -1.f, tid);
  int blk = blockIdx.x;
  const float* in;
  float2* out;
  if (blk < 16384) {
    in = xin + (long)blk * 8 * 256;
    out = xout + (long)blk * 8 * PITCH;
  } else {
    blk -= 16384;
    in = win + (long)blk * 8 * 256;
    out = wout + (long)blk * 8 * PITCH;
  }
  const int p = tid >> 6, lt = tid & 63;
  float2* s = sc + p * 272;
  {  // load rows 2p, 2p+1; pack; digit-reversed scatter
    int n0 = lt * 4;
    float4 v0 = *(const float4*)(in + (2 * p) * 256 + n0);
    float4 v1 = *(const float4*)(in + (2 * p + 1) * 256 + n0);
    s[SW(drev4(n0))]     = make_float2(v0.x, v1.x);
    s[SW(drev4(n0 + 1))] = make_float2(v0.y, v1.y);
    s[SW(drev4(n0 + 2))] = make_float2(v0.z, v1.z);
    s[SW(drev4(n0 + 3))] = make_float2(v0.w, v1.w);
  }
  __syncthreads();
#pragma unroll
  for (int st = 0; st < 4; ++st) {
    const int sh2 = 2 * st;
    const int L = 1 << sh2;
    const int sh = 6 - sh2;
    int j = lt & (L - 1);
    int i0 = ((lt >> sh2) << (sh2 + 2)) + j;
    float2 t1 = tw[j << sh];
    float2 t2 = tw[(2 * j) << sh];
    float2 t3 = tw[(3 * j) << sh];
    float2 x0 = s[SW(i0)], x1 = s[SW(i0 + L)];
    float2 x2 = s[SW(i0 + 2 * L)], x3 = s[SW(i0 + 3 * L)];
    float2 y0, y1, y2, y3;
    bfly4<-1>(x0, x1, x2, x3, t1, t2, t3, y0, y1, y2, y3);
    s[SW(i0)] = y0;
    s[SW(i0 + L)] = y1;
    s[SW(i0 + 2 * L)] = y2;
    s[SW(i0 + 3 * L)] = y3;
    __syncthreads();
  }
  // unpack: A[k] = (Z[k]+conj(Z[-k]))/2, B[k] = -i/2*(Z[k]-conj(Z[-k]))
  float2* op0 = out + (2 * p) * PITCH;
  float2* op1 = out + (2 * p + 1) * PITCH;
#pragma unroll
  for (int half = 0; half < 2; ++half) {
    int k = lt + 64 * half;
    float2 U = s[SW(k)];
    float2 Vc = s[SW((256 - k) & 255)];
    float2 V = make_float2(Vc.x, -Vc.y);
    float2 A = make_float2(0.5f * (U.x + V.x), 0.5f * (U.y + V.y));
    float Wx = U.x - V.x, Wy = U.y - V.y;
    float2 Bv = make_float2(0.5f * Wy, -0.5f * Wx);
    op0[k] = A;
    op1[k] = Bv;
  }
  if (lt == 0) {
    float2 Z = s[SW(128)];
    op0[128] = make_float2(Z.x, 0.f);
    op1[128] = make_float2(Z.y, 0.f);
  }
}

// ---------------- complex FFT along H, in place; tile 256h x TW_ wb --------
template <int SIGN, int TW_>
__device__ __forceinline__ void fft_cols_body(float2* __restrict__ base,
                                              float2* __restrict__ sc,
                                              const float2* __restrict__ tw,
                                              int tid) {
  constexpr int LGT = (TW_ == 16) ? 4 : 3;
#pragma unroll
  for (int r = 0; r < TW_ / 2; ++r) {  // load, digit-reversed on h
    int f = r * 256 + tid;
    int c2 = f & (TW_ / 2 - 1);
    int h = f >> (LGT - 1);
    float4 v = *(const float4*)(base + (long)h * PITCH + c2 * 2);
    int hb = drev4(h);
    sc[hb * TW_ + c2 * 2]     = make_float2(v.x, v.y);
    sc[hb * TW_ + c2 * 2 + 1] = make_float2(v.z, v.w);
  }
  __syncthreads();
#pragma unroll
  for (int st = 0; st < 4; ++st) {
    const int sh2 = 2 * st;
    const int L = 1 << sh2;
    const int sh = 6 - sh2;
#pragma unroll
    for (int q = 0; q < TW_ / 4; ++q) {
      int e = q * 256 + tid;
      int col = e & (TW_ - 1);
      int k = e >> LGT;
      int j = k & (L - 1);
      int i0 = ((k >> sh2) << (sh2 + 2)) + j;
      float2 t1 = tw[j << sh];
      float2 t2 = tw[(2 * j) << sh];
      float2 t3 = tw[(3 * j) << sh];
      float2* p0 = &sc[i0 * TW_ + col];
      float2 x0 = p0[0], x1 = p0[L * TW_], x2 = p0[2 * L * TW_], x3 = p0[3 * L * TW_];
      float2 y0, y1, y2, y3;
      bfly4<SIGN>(x0, x1, x2, x3, t1, t2, t3, y0, y1, y2, y3);
      p0[0] = y0;
      p0[L * TW_] = y1;
      p0[2 * L * TW_] = y2;
      p0[3 * L * TW_] = y3;
    }
    __syncthreads();
  }
#pragma unroll
  for (int r = 0; r < TW_ / 2; ++r) {  // store, natural order
    int f = r * 256 + tid;
    int c2 = f & (TW_ / 2 - 1);
    int h = f >> (LGT - 1);
    float2 a = sc[h * TW_ + c2 * 2], b = sc[h * TW_ + c2 * 2 + 1];
    *(float4*)(base + (long)h * PITCH + c2 * 2) = make_float4(a.x, a.y, b.x, b.y);
  }
}

template <int SIGN>
__global__ __launch_bounds__(256) void fft_cols(float2* __restrict__ data) {
  __shared__ float2 sc[256 * 16];
  __shared__ float2 tw[256];
  const int tid = threadIdx.x;
  fill_tw256(tw, (float)SIGN, tid);
  if (blockIdx.y < 8) {
    float2* base = data + (long)blockIdx.x * 256 * PITCH + blockIdx.y * 16;
    fft_cols_body<SIGN, 16>(base, sc, tw, tid);
  } else {  // Nyquist tail: bins 128..135 (129..135 are in-pitch pad garbage)
    float2* base = data + (long)blockIdx.x * 256 * PITCH + 128;
    fft_cols_body<SIGN, 8>(base, sc, tw, tid);
  }
}

// ---------------- per-bin contraction over C -------------------------------
// grid (256 h, 9): y<8 = 16-wide wb tiles with register-prefetch pipeline,
// y==8 = Nyquist column (wb=128). In place: Out rows b*32+o overwrite X rows.
__global__ __launch_bounds__(256, 3) void einsum_kernel(float2* __restrict__ xf,
                                                        const float2* __restrict__ wf) {
  __shared__ __align__(16) float2 Xs[8 * 256];      // [c][b*16+wb]
  __shared__ __align__(16) float2 Ws[8 * 32 * 16];  // [c][o][wb]
  const int h = blockIdx.x;
  const int tid = threadIdx.x;

  if (blockIdx.y == 8) {  // ---- Nyquist column ----
    const long off = (long)h * PITCH + 128;
    for (int e = tid; e < 512; e += 256)  Xs[e] = xf[(long)e * 256 * PITCH + off];
    for (int e = tid; e < 1024; e += 256) Ws[e] = wf[(long)e * 256 * PITCH + off];
    __syncthreads();
    const int b = tid >> 4, o0 = (tid & 15) * 2;
    float2 a0 = make_float2(0.f, 0.f), a1 = make_float2(0.f, 0.f);
#pragma unroll
    for (int c = 0; c < 32; ++c) {
      float2 x = Xs[b * 32 + c];
      float2 w0 = Ws[o0 * 32 + c];
      float2 w1 = Ws[(o0 + 1) * 32 + c];
      a0.x = fmaf(x.x, w0.x, fmaf(-x.y, w0.y, a0.x));
      a0.y = fmaf(x.x, w0.y, fmaf(x.y, w0.x, a0.y));
      a1.x = fmaf(x.x, w1.x, fmaf(-x.y, w1.y, a1.x));
      a1.y = fmaf(x.x, w1.y, fmaf(x.y, w1.x, a1.y));
    }
    xf[(long)(b * 32 + o0) * 256 * PITCH + off] = a0;
    xf[(long)(b * 32 + o0 + 1) * 256 * PITCH + off] = a1;
    return;
  }

  const int wb = tid & 15, b = tid >> 4;
  const long hoff = (long)h * PITCH + blockIdx.y * 16;
  float2 acc[32];
#pragma unroll
  for (int o = 0; o < 32; ++o) acc[o] = make_float2(0.f, 0.f);

  // per-thread staging addresses
  const float2* gX[4];
  float2* sX[4];
#pragma unroll
  for (int r = 0; r < 4; ++r) {
    int e = r * 256 + tid, lw = e & 7, lc = (e >> 3) & 7, lb = e >> 6;
    gX[r] = xf + (long)(lb * 32 + lc) * 256 * PITCH + hoff + lw * 2;
    sX[r] = &Xs[lc * 256 + lb * 16 + lw * 2];
  }
  const float2* gW[8];
  float2* sW[8];
#pragma unroll
  for (int r = 0; r < 8; ++r) {
    int e = r * 256 + tid, lw = e & 7, lc = (e >> 3) & 7, lo = e >> 6;
    gW[r] = wf + (long)(lo * 32 + lc) * 256 * PITCH + hoff + lw * 2;
    sW[r] = &Ws[(lc * 32 + lo) * 16 + lw * 2];
  }
  const long cstep = (long)8 * 256 * PITCH;

  // prologue: c-tile 0 -> registers
  float4 px[4], pw[8];
#pragma unroll
  for (int r = 0; r < 4; ++r) px[r] = *(const float4*)gX[r];
#pragma unroll
  for (int r = 0; r < 8; ++r) pw[r] = *(const float4*)gW[r];

  for (int c0 = 0; c0 < 32; c0 += 8) {
    // staged regs -> LDS
#pragma unroll
    for (int r = 0; r < 4; ++r) *(float4*)sX[r] = px[r];
#pragma unroll
    for (int r = 0; r < 8; ++r) *(float4*)sW[r] = pw[r];
    __syncthreads();
    // issue next tile's loads early; latency hides under compute below
    if (c0 < 24) {
#pragma unroll
      for (int r = 0; r < 4; ++r) { gX[r] += cstep; px[r] = *(const float4*)gX[r]; }
#pragma unroll
      for (int r = 0; r < 8; ++r) { gW[r] += cstep; pw[r] = *(const float4*)gW[r]; }
    }
#pragma unroll
    for (int c = 0; c < 8; ++c) {
      float2 xv = Xs[c * 256 + tid];       // lane-consecutive: conflict-free
#pragma unroll
      for (int o = 0; o < 32; ++o) {
        float2 wv = Ws[(c * 32 + o) * 16 + wb];  // 128B broadcast: conflict-free
        acc[o].x = fmaf(xv.x, wv.x, fmaf(-xv.y, wv.y, acc[o].x));
        acc[o].y = fmaf(xv.x, wv.y, fmaf(xv.y, wv.x, acc[o].y));
      }
    }
    __syncthreads();
  }
#pragma unroll
  for (int o = 0; o < 32; ++o)
    xf[(long)(b * 32 + o) * 256 * PITCH + hoff + wb] = acc[o];
}

// ---------------- inverse real FFT along W ---------------------------------
// 8 real output rows per block = 4 packed inverse complex FFTs
// (Z = Y0 + i*Y1 with Hermitian extension; Re -> row0, Im -> row1).
__global__ __launch_bounds__(256) void irfft_rows(const float2* __restrict__ in,
                                                  float* __restrict__ out) {
  __shared__ float2 sc[4 * 272];
  __shared__ float2 tw[256];
  const int tid = threadIdx.x;
  fill_tw256(tw, 1.f, tid);
  const long row0 = (long)blockIdx.x * 8;
  const int p = tid >> 6, lt = tid & 63;
  float2* s = sc + p * 272;
  const float2* ip0 = in + (row0 + 2 * p) * PITCH;
  const float2* ip1 = in + (row0 + 2 * p + 1) * PITCH;
#pragma unroll
  for (int q = 0; q < 4; ++q) {
    int k = lt + 64 * q;
    int m = (k <= 128) ? k : 256 - k;
    float2 U0 = ip0[m], U1 = ip1[m];
    float2 z;
    if (k <= 128) z = make_float2(U0.x - U1.y, U0.y + U1.x);
    else          z = make_float2(U0.x + U1.y, U1.x - U0.y);  // conj(U0)+i*conj(U1)
    s[SW(drev4(k))] = z;
  }
  __syncthreads();
#pragma unroll
  for (int st = 0; st < 4; ++st) {
    const int sh2 = 2 * st;
    const int L = 1 << sh2;
    const int sh = 6 - sh2;
    int j = lt & (L - 1);
    int i0 = ((lt >> sh2) << (sh2 + 2)) + j;
    float2 t1 = tw[j << sh];
    float2 t2 = tw[(2 * j) << sh];
    float2 t3 = tw[(3 * j) << sh];
    float2 x0 = s[SW(i0)], x1 = s[SW(i0 + L)];
    float2 x2 = s[SW(i0 + 2 * L)], x3 = s[SW(i0 + 3 * L)];
    float2 y0, y1, y2, y3;
    bfly4<1>(x0, x1, x2, x3, t1, t2, t3, y0, y1, y2, y3);
    s[SW(i0)] = y0;
    s[SW(i0 + L)] = y1;
    s[SW(i0 + 2 * L)] = y2;
    s[SW(i0 + 3 * L)] = y3;
    __syncthreads();
  }
  const float scale = 1.f / 65536.f;  // 1/(H*W)
  float* o0 = out + (row0 + 2 * p) * 256;
  float* o1 = out + (row0 + 2 * p + 1) * 256;
  int n0 = lt * 4;
  float2 e0 = s[SW(n0)], e1 = s[SW(n0 + 1)], e2 = s[SW(n0 + 2)], e3 = s[SW(n0 + 3)];
  *(float4*)(o0 + n0) = make_float4(e0.x * scale, e1.x * scale, e2.x * scale, e3.x * scale);
  *(float4*)(o1 + n0) = make_float4(e0.y * scale, e1.y * scale, e2.y * scale, e3.y * scale);
}

extern "C" void kernel_launch(void* const* d_in, const int* in_sizes, int n_in,
                              void* d_out, int out_size, void* d_ws, size_t ws_size,
                              hipStream_t stream) {
  const float* x = (const float*)d_in[0];   // (16,32,256,256)
  const float* w = (const float*)d_in[1];   // (32,32,256,256)
  float* out = (float*)d_out;               // (16,32,256,256)

  const size_t row_elems = (size_t)256 * PITCH;
  const size_t need = (size_t)(512 + 1024) * row_elems * sizeof(float2);
  if (ws_size < need) return;

  float2* Xf = (float2*)d_ws;
  float2* Wf = Xf + (size_t)512 * row_elems;

  // 1) forward row rffts, x and w in one launch (8 rows / block, pack trick)
  rfft_rows<<<dim3(16384 + 32768), 256, 0, stream>>>(x, w, Xf, Wf);
  // 2) forward column ffts over contiguous Xf||Wf (y==8 handles Nyquist tail)
  fft_cols<-1><<<dim3(1536, 9), 256, 0, stream>>>(Xf);
  // 3) contraction (y==8 handles Nyquist column)
  einsum_kernel<<<dim3(256, 9), 256, 0, stream>>>(Xf, Wf);
  // 4) inverse column ffts on Out_f
  fft_cols<1><<<dim3(512, 9), 256, 0, stream>>>(Xf);
  // 5) inverse row rffts -> real output (scaled 1/65536)
  irfft_rows<<<dim3(16384), 256, 0, stream>>>(Xf, out);
}

// Round 5
// 1038.656 us; speedup vs baseline: 1.0444x; 1.0444x over previous
//
#include <hip/hip_runtime.h>
#include <math.h>

// FFT conv2d: out = irfft2( einsum("bchw,ochw->bohw", rfft2(x), rfft2(w)) )
// B=16, C=32, O=32, H=W=256. fp32.
// Freq layout: flat[(row*256 + h)*PITCH + wb], row = b*32+c (or o*32+c / b*32+o),
// wb in [0,129); PITCH=136 complex keeps every (row,h) line 64B-aligned.
//
// R2 (resubmitted; R3/R4 lost to GPU acquisition timeouts):
// einsum reverted to R0 structure (R1 prefetch doubled HBM traffic via L3
// thrash: fetch 296->494MB, write 167->528MB). fft_cols main path rewritten as
// radix-16^2: 2 register-resident DFT16 stages, constant internal twiddles,
// natural order (no digit reversal), conflict-free LDS by wb-fast layout.

#define PITCH 136
#define SW(i) ((i) + ((i) >> 4))   // row-FFT LDS swizzle; region = 272 float2

__device__ __forceinline__ int drev4(int x) {  // base-4 digit reversal of 8-bit x
  int r = (int)(__brev((unsigned)x) >> 24);
  return ((r & 0x55) << 1) | ((r >> 1) & 0x55);
}

// tw[n] = exp(sign * 2*pi*i * n / 256), n in [0,256)
__device__ __forceinline__ void fill_tw256(float2* tw, float sign, int tid) {
  float ang = sign * 6.2831853071795864769f * (float)tid * (1.0f / 256.0f);
  float s, c;
  __sincosf(ang, &s, &c);
  tw[tid] = make_float2(c, s);
}

__device__ __forceinline__ float2 cmul(float2 a, float2 b) {
  return make_float2(fmaf(a.x, b.x, -(a.y * b.y)), fmaf(a.x, b.y, a.y * b.x));
}

// radix-4 DIT butterfly: a_c = x_c * t_c (t0=1), y_q = sum_c a_c * w4^(q*c),
// w4 = exp(SIGN*2*pi*i/4) = SIGN*i
template <int SIGN>
__device__ __forceinline__ void bfly4(float2 x0, float2 x1, float2 x2, float2 x3,
                                      float2 t1, float2 t2, float2 t3,
                                      float2& y0, float2& y1, float2& y2, float2& y3) {
  float2 a1 = cmul(x1, t1);
  float2 a2 = cmul(x2, t2);
  float2 a3 = cmul(x3, t3);
  float Ax = x0.x + a2.x, Ay = x0.y + a2.y;
  float Bx = x0.x - a2.x, By = x0.y - a2.y;
  float Cx = a1.x + a3.x, Cy = a1.y + a3.y;
  float Dx = a1.x - a3.x, Dy = a1.y - a3.y;
  y0 = make_float2(Ax + Cx, Ay + Cy);
  y2 = make_float2(Ax - Cx, Ay - Cy);
  if (SIGN == 1) {
    y1 = make_float2(Bx - Dy, By + Dx);
    y3 = make_float2(Bx + Dy, By - Dx);
  } else {
    y1 = make_float2(Bx + Dy, By - Dx);
    y3 = make_float2(Bx - Dy, By + Dx);
  }
}

// In-register 16-point DFT, natural in/out: v[k] = sum_n v[n] w16^(n*k),
// w16 = exp(SIGN*2*pi*i/16). All twiddles are compile-time constants.
template <int SIGN>
__device__ __forceinline__ void dft16(float2 v[16]) {
  const float C1 = 0.92387953251128675613f;  // cos(pi/8)
  const float S1 = 0.38268343236508977173f;  // sin(pi/8)
  const float R2 = 0.70710678118654752440f;
  const float s = (float)SIGN;
  const float2 ONE = make_float2(1.f, 0.f);
  const float2 W1 = make_float2(C1, s * S1);
  const float2 W2 = make_float2(R2, s * R2);
  const float2 W3 = make_float2(S1, s * C1);
  const float2 W4 = make_float2(0.f, s);
  const float2 W6 = make_float2(-R2, s * R2);
  const float2 W9 = make_float2(-C1, -s * S1);
  float2 t[4][4];
#pragma unroll
  for (int b = 0; b < 4; ++b)
    bfly4<SIGN>(v[b], v[b + 4], v[b + 8], v[b + 12], ONE, ONE, ONE,
                t[b][0], t[b][1], t[b][2], t[b][3]);
  t[1][1] = cmul(t[1][1], W1); t[1][2] = cmul(t[1][2], W2); t[1][3] = cmul(t[1][3], W3);
  t[2][1] = cmul(t[2][1], W2); t[2][2] = cmul(t[2][2], W4); t[2][3] = cmul(t[2][3], W6);
  t[3][1] = cmul(t[3][1], W3); t[3][2] = cmul(t[3][2], W6); t[3][3] = cmul(t[3][3], W9);
#pragma unroll
  for (int k1 = 0; k1 < 4; ++k1)
    bfly4<SIGN>(t[0][k1], t[1][k1], t[2][k1], t[3][k1], ONE, ONE, ONE,
                v[k1], v[k1 + 4], v[k1 + 8], v[k1 + 12]);
}

// ---------------- forward real FFT along W ---------------------------------
// 8 real rows per 256-thread block = 4 packed complex FFTs (z = rowA + i*rowB).
// Handles both x (blocks [0,16384)) and w (blocks [16384,49152)).
__global__ __launch_bounds__(256) void rfft_rows(const float* __restrict__ xin,
                                                 const float* __restrict__ win,
                                                 float2* __restrict__ xout,
                                                 float2* __restrict__ wout) {
  __shared__ float2 sc[4 * 272];
  __shared__ float2 tw[256];
  const int tid = threadIdx.x;
  fill_tw256(tw, -1.f, tid);
  int blk = blockIdx.x;
  const float* in;
  float2* out;
  if (blk < 16384) {
    in = xin + (long)blk * 8 * 256;
    out = xout + (long)blk * 8 * PITCH;
  } else {
    blk -= 16384;
    in = win + (long)blk * 8 * 256;
    out = wout + (long)blk * 8 * PITCH;
  }
  const int p = tid >> 6, lt = tid & 63;
  float2* s = sc + p * 272;
  {  // load rows 2p, 2p+1; pack; digit-reversed scatter
    int n0 = lt * 4;
    float4 v0 = *(const float4*)(in + (2 * p) * 256 + n0);
    float4 v1 = *(const float4*)(in + (2 * p + 1) * 256 + n0);
    s[SW(drev4(n0))]     = make_float2(v0.x, v1.x);
    s[SW(drev4(n0 + 1))] = make_float2(v0.y, v1.y);
    s[SW(drev4(n0 + 2))] = make_float2(v0.z, v1.z);
    s[SW(drev4(n0 + 3))] = make_float2(v0.w, v1.w);
  }
  __syncthreads();
#pragma unroll
  for (int st = 0; st < 4; ++st) {
    const int sh2 = 2 * st;
    const int L = 1 << sh2;
    const int sh = 6 - sh2;
    int j = lt & (L - 1);
    int i0 = ((lt >> sh2) << (sh2 + 2)) + j;
    float2 t1 = tw[j << sh];
    float2 t2 = tw[(2 * j) << sh];
    float2 t3 = tw[(3 * j) << sh];
    float2 x0 = s[SW(i0)], x1 = s[SW(i0 + L)];
    float2 x2 = s[SW(i0 + 2 * L)], x3 = s[SW(i0 + 3 * L)];
    float2 y0, y1, y2, y3;
    bfly4<-1>(x0, x1, x2, x3, t1, t2, t3, y0, y1, y2, y3);
    s[SW(i0)] = y0;
    s[SW(i0 + L)] = y1;
    s[SW(i0 + 2 * L)] = y2;
    s[SW(i0 + 3 * L)] = y3;
    __syncthreads();
  }
  // unpack: A[k] = (Z[k]+conj(Z[-k]))/2, B[k] = -i/2*(Z[k]-conj(Z[-k]))
  float2* op0 = out + (2 * p) * PITCH;
  float2* op1 = out + (2 * p + 1) * PITCH;
#pragma unroll
  for (int half = 0; half < 2; ++half) {
    int k = lt + 64 * half;
    float2 U = s[SW(k)];
    float2 Vc = s[SW((256 - k) & 255)];
    float2 V = make_float2(Vc.x, -Vc.y);
    float2 A = make_float2(0.5f * (U.x + V.x), 0.5f * (U.y + V.y));
    float Wx = U.x - V.x, Wy = U.y - V.y;
    float2 Bv = make_float2(0.5f * Wy, -0.5f * Wx);
    op0[k] = A;
    op1[k] = Bv;
  }
  if (lt == 0) {
    float2 Z = s[SW(128)];
    op0[128] = make_float2(Z.x, 0.f);
    op1[128] = make_float2(Z.y, 0.f);
  }
}

// ------------- complex FFT along H: radix-16^2 main body (16-wide tile) ----
// Thread = (wb = tid&15, n1 = tid>>4). LDS layout sc[h*16 + wb]: the 16-wb
// fast dim spans all 32 banks per quarter-wave -> conflict-free everywhere.
template <int SIGN>
__device__ __forceinline__ void fft_cols_body16(float2* __restrict__ base,
                                                float2* __restrict__ sc,
                                                const float2* __restrict__ tw,
                                                int tid) {
#pragma unroll
  for (int r = 0; r < 8; ++r) {  // load, natural order
    int f = r * 256 + tid;
    int c2 = f & 7;
    int h = f >> 3;
    float4 v = *(const float4*)(base + (long)h * PITCH + c2 * 2);
    sc[h * 16 + c2 * 2]     = make_float2(v.x, v.y);
    sc[h * 16 + c2 * 2 + 1] = make_float2(v.z, v.w);
  }
  __syncthreads();
  const int wb = tid & 15, n1 = tid >> 4;
  // stage 1: DFT16 over n2 at fixed n1, then twiddle w256^(n1*K)
  float2 xr[16];
#pragma unroll
  for (int n2 = 0; n2 < 16; ++n2) xr[n2] = sc[(16 * n2 + n1) * 16 + wb];
  dft16<SIGN>(xr);
#pragma unroll
  for (int K = 1; K < 16; ++K) xr[K] = cmul(xr[K], tw[n1 * K]);
  __syncthreads();  // split read/write: write set differs from read set
#pragma unroll
  for (int K = 0; K < 16; ++K) sc[(n1 * 16 + K) * 16 + wb] = xr[K];
  __syncthreads();
  // stage 2: DFT16 over n1 at fixed k1; in-place safe (read set == write set)
  const int k1 = tid >> 4;
  float2 zr[16];
#pragma unroll
  for (int m = 0; m < 16; ++m) zr[m] = sc[(m * 16 + k1) * 16 + wb];
  dft16<SIGN>(zr);
#pragma unroll
  for (int k2 = 0; k2 < 16; ++k2) sc[(k1 + 16 * k2) * 16 + wb] = zr[k2];
  __syncthreads();
#pragma unroll
  for (int r = 0; r < 8; ++r) {  // store, natural order
    int f = r * 256 + tid;
    int c2 = f & 7;
    int h = f >> 3;
    float2 a = sc[h * 16 + c2 * 2], b = sc[h * 16 + c2 * 2 + 1];
    *(float4*)(base + (long)h * PITCH + c2 * 2) = make_float4(a.x, a.y, b.x, b.y);
  }
}

// radix-4 tail body (8-wide tile, bins 128..135; 129..135 are pad garbage)
template <int SIGN>
__device__ __forceinline__ void fft_cols_body8(float2* __restrict__ base,
                                               float2* __restrict__ sc,
                                               const float2* __restrict__ tw,
                                               int tid) {
  constexpr int TW_ = 8, LGT = 3;
#pragma unroll
  for (int r = 0; r < TW_ / 2; ++r) {
    int f = r * 256 + tid;
    int c2 = f & (TW_ / 2 - 1);
    int h = f >> (LGT - 1);
    float4 v = *(const float4*)(base + (long)h * PITCH + c2 * 2);
    int hb = drev4(h);
    sc[hb * TW_ + c2 * 2]     = make_float2(v.x, v.y);
    sc[hb * TW_ + c2 * 2 + 1] = make_float2(v.z, v.w);
  }
  __syncthreads();
#pragma unroll
  for (int st = 0; st < 4; ++st) {
    const int sh2 = 2 * st;
    const int L = 1 << sh2;
    const int sh = 6 - sh2;
#pragma unroll
    for (int q = 0; q < TW_ / 4; ++q) {
      int e = q * 256 + tid;
      int col = e & (TW_ - 1);
      int k = e >> LGT;
      int j = k & (L - 1);
      int i0 = ((k >> sh2) << (sh2 + 2)) + j;
      float2 t1 = tw[j << sh];
      float2 t2 = tw[(2 * j) << sh];
      float2 t3 = tw[(3 * j) << sh];
      float2* p0 = &sc[i0 * TW_ + col];
      float2 x0 = p0[0], x1 = p0[L * TW_], x2 = p0[2 * L * TW_], x3 = p0[3 * L * TW_];
      float2 y0, y1, y2, y3;
      bfly4<SIGN>(x0, x1, x2, x3, t1, t2, t3, y0, y1, y2, y3);
      p0[0] = y0;
      p0[L * TW_] = y1;
      p0[2 * L * TW_] = y2;
      p0[3 * L * TW_] = y3;
    }
    __syncthreads();
  }
#pragma unroll
  for (int r = 0; r < TW_ / 2; ++r) {
    int f = r * 256 + tid;
    int c2 = f & (TW_ / 2 - 1);
    int h = f >> (LGT - 1);
    float2 a = sc[h * TW_ + c2 * 2], b = sc[h * TW_ + c2 * 2 + 1];
    *(float4*)(base + (long)h * PITCH + c2 * 2) = make_float4(a.x, a.y, b.x, b.y);
  }
}

template <int SIGN>
__global__ __launch_bounds__(256) void fft_cols(float2* __restrict__ data) {
  __shared__ float2 sc[256 * 16];
  __shared__ float2 tw[256];
  const int tid = threadIdx.x;
  fill_tw256(tw, (float)SIGN, tid);
  __syncthreads();
  if (blockIdx.y < 8) {
    float2* base = data + (long)blockIdx.x * 256 * PITCH + blockIdx.y * 16;
    fft_cols_body16<SIGN>(base, sc, tw, tid);
  } else {
    float2* base = data + (long)blockIdx.x * 256 * PITCH + 128;
    fft_cols_body8<SIGN>(base, sc, tw, tid);
  }
}

// ---------------- per-bin contraction over C -------------------------------
// grid (256 h, 9): y<8 = 16-wide wb tiles (R0 structure: direct global->LDS
// staging, no prefetch), y==8 = Nyquist column (wb=128). In place.
__global__ __launch_bounds__(256, 3) void einsum_kernel(float2* __restrict__ xf,
                                                        const float2* __restrict__ wf) {
  __shared__ float2 Xs[8 * 256];      // [c][b*16+wb]
  __shared__ float2 Ws[8 * 32 * 16];  // [c][o][wb]
  const int h = blockIdx.x;
  const int tid = threadIdx.x;

  if (blockIdx.y == 8) {  // ---- Nyquist column ----
    const long off = (long)h * PITCH + 128;
    for (int e = tid; e < 512; e += 256)  Xs[e] = xf[(long)e * 256 * PITCH + off];
    for (int e = tid; e < 1024; e += 256) Ws[e] = wf[(long)e * 256 * PITCH + off];
    __syncthreads();
    const int b = tid >> 4, o0 = (tid & 15) * 2;
    float2 a0 = make_float2(0.f, 0.f), a1 = make_float2(0.f, 0.f);
#pragma unroll
    for (int c = 0; c < 32; ++c) {
      float2 x = Xs[b * 32 + c];
      float2 w0 = Ws[o0 * 32 + c];
      float2 w1 = Ws[(o0 + 1) * 32 + c];
      a0.x = fmaf(x.x, w0.x, fmaf(-x.y, w0.y, a0.x));
      a0.y = fmaf(x.x, w0.y, fmaf(x.y, w0.x, a0.y));
      a1.x = fmaf(x.x, w1.x, fmaf(-x.y, w1.y, a1.x));
      a1.y = fmaf(x.x, w1.y, fmaf(x.y, w1.x, a1.y));
    }
    xf[(long)(b * 32 + o0) * 256 * PITCH + off] = a0;
    xf[(long)(b * 32 + o0 + 1) * 256 * PITCH + off] = a1;
    return;
  }

  const int wb = tid & 15, b = tid >> 4;
  const long hoff = (long)h * PITCH + blockIdx.y * 16;
  float2 acc[32];
#pragma unroll
  for (int o = 0; o < 32; ++o) acc[o] = make_float2(0.f, 0.f);

  for (int c0 = 0; c0 < 32; c0 += 8) {
#pragma unroll
    for (int r = 0; r < 4; ++r) {          // X: 16b x 8c rows, 8 float4 each
      int e = r * 256 + tid;
      int lw = e & 7, lc = (e >> 3) & 7, lb = e >> 6;
      float4 v = *(const float4*)(xf + (long)(lb * 32 + c0 + lc) * 256 * PITCH + hoff + lw * 2);
      Xs[lc * 256 + lb * 16 + lw * 2]     = make_float2(v.x, v.y);
      Xs[lc * 256 + lb * 16 + lw * 2 + 1] = make_float2(v.z, v.w);
    }
#pragma unroll
    for (int r = 0; r < 8; ++r) {          // W: 32o x 8c rows
      int e = r * 256 + tid;
      int lw = e & 7, lc = (e >> 3) & 7, lo = e >> 6;
      float4 v = *(const float4*)(wf + (long)(lo * 32 + c0 + lc) * 256 * PITCH + hoff + lw * 2);
      Ws[(lc * 32 + lo) * 16 + lw * 2]     = make_float2(v.x, v.y);
      Ws[(lc * 32 + lo) * 16 + lw * 2 + 1] = make_float2(v.z, v.w);
    }
    __syncthreads();
#pragma unroll
    for (int c = 0; c < 8; ++c) {
      float2 xv = Xs[c * 256 + tid];       // lane-consecutive: conflict-free
#pragma unroll
      for (int o = 0; o < 32; ++o) {
        float2 wv = Ws[(c * 32 + o) * 16 + wb];  // 128B broadcast: conflict-free
        acc[o].x = fmaf(xv.x, wv.x, fmaf(-xv.y, wv.y, acc[o].x));
        acc[o].y = fmaf(xv.x, wv.y, fmaf(xv.y, wv.x, acc[o].y));
      }
    }
    __syncthreads();
  }
#pragma unroll
  for (int o = 0; o < 32; ++o)
    xf[(long)(b * 32 + o) * 256 * PITCH + hoff + wb] = acc[o];
}

// ---------------- inverse real FFT along W ---------------------------------
// 8 real output rows per block = 4 packed inverse complex FFTs
// (Z = Y0 + i*Y1 with Hermitian extension; Re -> row0, Im -> row1).
__global__ __launch_bounds__(256) void irfft_rows(const float2* __restrict__ in,
                                                  float* __restrict__ out) {
  __shared__ float2 sc[4 * 272];
  __shared__ float2 tw[256];
  const int tid = threadIdx.x;
  fill_tw256(tw, 1.f, tid);
  const long row0 = (long)blockIdx.x * 8;
  const int p = tid >> 6, lt = tid & 63;
  float2* s = sc + p * 272;
  const float2* ip0 = in + (row0 + 2 * p) * PITCH;
  const float2* ip1 = in + (row0 + 2 * p + 1) * PITCH;
#pragma unroll
  for (int q = 0; q < 4; ++q) {
    int k = lt + 64 * q;
    int m = (k <= 128) ? k : 256 - k;
    float2 U0 = ip0[m], U1 = ip1[m];
    float2 z;
    if (k <= 128) z = make_float2(U0.x - U1.y, U0.y + U1.x);
    else          z = make_float2(U0.x + U1.y, U1.x - U0.y);  // conj(U0)+i*conj(U1)
    s[SW(drev4(k))] = z;
  }
  __syncthreads();
#pragma unroll
  for (int st = 0; st < 4; ++st) {
    const int sh2 = 2 * st;
    const int L = 1 << sh2;
    const int sh = 6 - sh2;
    int j = lt & (L - 1);
    int i0 = ((lt >> sh2) << (sh2 + 2)) + j;
    float2 t1 = tw[j << sh];
    float2 t2 = tw[(2 * j) << sh];
    float2 t3 = tw[(3 * j) << sh];
    float2 x0 = s[SW(i0)], x1 = s[SW(i0 + L)];
    float2 x2 = s[SW(i0 + 2 * L)], x3 = s[SW(i0 + 3 * L)];
    float2 y0, y1, y2, y3;
    bfly4<1>(x0, x1, x2, x3, t1, t2, t3, y0, y1, y2, y3);
    s[SW(i0)] = y0;
    s[SW(i0 + L)] = y1;
    s[SW(i0 + 2 * L)] = y2;
    s[SW(i0 + 3 * L)] = y3;
    __syncthreads();
  }
  const float scale = 1.f / 65536.f;  // 1/(H*W)
  float* o0 = out + (row0 + 2 * p) * 256;
  float* o1 = out + (row0 + 2 * p + 1) * 256;
  int n0 = lt * 4;
  float2 e0 = s[SW(n0)], e1 = s[SW(n0 + 1)], e2 = s[SW(n0 + 2)], e3 = s[SW(n0 + 3)];
  *(float4*)(o0 + n0) = make_float4(e0.x * scale, e1.x * scale, e2.x * scale, e3.x * scale);
  *(float4*)(o1 + n0) = make_float4(e0.y * scale, e1.y * scale, e2.y * scale, e3.y * scale);
}

extern "C" void kernel_launch(void* const* d_in, const int* in_sizes, int n_in,
                              void* d_out, int out_size, void* d_ws, size_t ws_size,
                              hipStream_t stream) {
  const float* x = (const float*)d_in[0];   // (16,32,256,256)
  const float* w = (const float*)d_in[1];   // (32,32,256,256)
  float* out = (float*)d_out;               // (16,32,256,256)

  const size_t row_elems = (size_t)256 * PITCH;
  const size_t need = (size_t)(512 + 1024) * row_elems * sizeof(float2);
  if (ws_size < need) return;

  float2* Xf = (float2*)d_ws;
  float2* Wf = Xf + (size_t)512 * row_elems;

  // 1) forward row rffts, x and w in one launch (8 rows / block, pack trick)
  rfft_rows<<<dim3(16384 + 32768), 256, 0, stream>>>(x, w, Xf, Wf);
  // 2) forward column ffts over contiguous Xf||Wf (y==8 handles Nyquist tail)
  fft_cols<-1><<<dim3(1536, 9), 256, 0, stream>>>(Xf);
  // 3) contraction (y==8 handles Nyquist column)
  einsum_kernel<<<dim3(256, 9), 256, 0, stream>>>(Xf, Wf);
  // 4) inverse column ffts on Out_f
  fft_cols<1><<<dim3(512, 9), 256, 0, stream>>>(Xf);
  // 5) inverse row rffts -> real output (scaled 1/65536)
  irfft_rows<<<dim3(16384), 256, 0, stream>>>(Xf, out);
}